// Round 7
// baseline (33.275 us; speedup 1.0000x reference)
//
#include <hip/hip_runtime.h>
#include <hip/hip_bf16.h>
#include <utility>

#define CFEAT 128
#define NODES 2048
#define NM    219            // 9 deg1 + 45 deg2 + 165 deg3 monomials
#define NSTEP 14             // K padded to 224 = 14*16 (32x32x16 MFMA)

typedef __attribute__((ext_vector_type(8)))  short short8;
typedef __attribute__((ext_vector_type(16))) float f32x16;
typedef __attribute__((ext_vector_type(4)))  unsigned int uint4v;

// ---- ws offsets: [0, 1835008B) = Wf bf16 fragments (128*14*64*8*2B). ------
// fp32 scratch after 2MB:
#define OFF3 524288                          // U3s [9][165][16] floats
#define OFF2 (OFF3 + 9*165*16)               // U2s [9][45][4]
#define OFF1 (OFF2 + 9*45*4)                 // U1s [9][9]

__device__ __forceinline__ short f2bf(float x) {
    union { __hip_bfloat16 b; short s; } cv;
    cv.b = __float2bfloat16(x);
    return cv.s;
}

// ---- monomial index -> (deg,i,j,l), i<=j<=l (constexpr) --------------------
struct MIdx { int deg, i, j, l; };
__host__ __device__ constexpr MIdx decode_c(int idx) {
    if (idx < 9) return {1, idx, 0, 0};
    int t = idx - 9;
    for (int i = 0; i < 9; ++i)
        for (int j = i; j < 9; ++j) {
            int cnt = 10 - j;
            if (t < cnt) {
                if (t == 0) return {2, i, j, 0};
                return {3, i, j, j + t - 1};
            }
            t -= cnt;
        }
    return {0, 0, 0, 0};
}
__host__ __device__ constexpr int h2c(int n) { return n * (n + 1) / 2; }
__host__ __device__ constexpr int g3c(int n) { return n * (n + 1) * (n + 2) / 6; }
__host__ __device__ constexpr int tri3c(int i, int j, int l) {
    return (165 - g3c(9 - i)) + (h2c(9 - i) - h2c(9 - j)) + (l - j);
}
__host__ __device__ constexpr int pair2c(int i, int j) {
    return (45 - h2c(9 - i)) + (j - i);
}

// packed per-k table: deg | (sub-index << 4)
struct MTbl { int v[224]; };
__host__ __device__ constexpr MTbl gen_tbl() {
    MTbl t{};
    for (int k = 0; k < 224; ++k) {
        if (k < NM) {
            MIdx d = decode_c(k);
            int sub = (d.deg == 1) ? d.i : (d.deg == 2) ? pair2c(d.i, d.j)
                                                        : tri3c(d.i, d.j, d.l);
            t.v[k] = d.deg | (sub << 4);
        } else t.v[k] = 0;
    }
    return t;
}
__device__ constexpr MTbl MONO_TBL = gen_tbl();

template<int K>
__device__ __forceinline__ float mono_val_t(const float a[9]) {
    if constexpr (K >= NM) return 0.f;
    else {
        constexpr MIdx d = decode_c(K);
        if constexpr (d.deg == 1) return a[d.i];
        else if constexpr (d.deg == 2) return a[d.i] * a[d.j];
        else return a[d.i] * a[d.j] * a[d.l];
    }
}

// dword of two bf16 monomials (KB, KB+1): round-half-up + perm merge (validated r4-r6)
template<int KB>
__device__ __forceinline__ unsigned packd(const float a[9]) {
    return __builtin_amdgcn_perm(__float_as_uint(mono_val_t<KB + 1>(a)) + 0x8000u,
                                 __float_as_uint(mono_val_t<KB>(a)) + 0x8000u,
                                 0x07060302u);
}

// A-fragment for step S: lane-half hi takes k [S*16+8,+8), lo takes [S*16,+8)
template<int S>
__device__ __forceinline__ short8 build16(const float a[9], bool hi) {
    union { uint4v u; short8 s; } cv;
    cv.u = uint4v{ hi ? packd<S*16 +  8>(a) : packd<S*16 + 0>(a),
                   hi ? packd<S*16 + 10>(a) : packd<S*16 + 2>(a),
                   hi ? packd<S*16 + 12>(a) : packd<S*16 + 4>(a),
                   hi ? packd<S*16 + 14>(a) : packd<S*16 + 6>(a) };
    return cv.s;
}

// ---- P1: channel-independent symmetrization (unchanged math, new offsets) --
__global__ __launch_bounds__(256) void symcon_p1(
    const float* __restrict__ Us1, const float* __restrict__ Us2, const float* __restrict__ Us3,
    const float* __restrict__ Up1, const float* __restrict__ Up2, const float* __restrict__ Up3,
    const float* __restrict__ Ud1, const float* __restrict__ Ud2, const float* __restrict__ Ud3,
    float* __restrict__ ws_f)
{
    const int mg = blockIdx.x;
    const int y  = blockIdx.y;
    const int t  = threadIdx.x;

    const float *U1, *U2, *U3; int K2, K3, ml;
    if (mg == 0)     { U1 = Us1; U2 = Us2; U3 = Us3; K2 = 2; K3 = 5;  ml = 0; }
    else if (mg < 4) { U1 = Up1; U2 = Up2; U3 = Up3; K2 = 3; K3 = 8;  ml = mg - 1; }
    else             { U1 = Ud1; U2 = Ud2; U3 = Ud3; K2 = 4; K3 = 10; ml = mg - 4; }

    if (y < 11) {
        if (t >= 240) return;
        const int tri = y * 15 + (t >> 4);
        const int k   = t & 15;
        if (k >= K3) return;
        int i = 0, j = 0, l = 0, r = tri;
        bool done = false;
        for (i = 0; i < 9 && !done; ++i)
            for (j = i; j < 9; ++j) {
                int cnt = 9 - j;
                if (r < cnt) { l = j + r; done = true; break; }
                r -= cnt;
            }
        --i;
        const int e0=(i*9+j)*9+l, e1=(i*9+l)*9+j, e2=(j*9+i)*9+l,
                  e3=(j*9+l)*9+i, e4=(l*9+i)*9+j, e5=(l*9+j)*9+i;
        const float* B3 = U3 + (size_t)ml * 729 * K3 + k;
        float v = B3[(size_t)e0 * K3];
        if (e1 != e0)                                     v += B3[(size_t)e1 * K3];
        if (e2 != e0 && e2 != e1)                         v += B3[(size_t)e2 * K3];
        if (e3 != e0 && e3 != e1 && e3 != e2)             v += B3[(size_t)e3 * K3];
        if (e4 != e0 && e4 != e1 && e4 != e2 && e4 != e3) v += B3[(size_t)e4 * K3];
        if (e5 != e0 && e5 != e1 && e5 != e2 && e5 != e3 && e5 != e4)
                                                          v += B3[(size_t)e5 * K3];
        ws_f[OFF3 + (mg * 165 + tri) * 16 + k] = v;
    } else {
        if (t < 180) {
            int pr = t >> 2, k = t & 3;
            if (k >= K2) return;
            int i = 0, j = 0, r = pr;
            for (i = 0; i < 9; ++i) {
                int cnt = 9 - i;
                if (r < cnt) { j = i + r; break; }
                r -= cnt;
            }
            float v = U2[((size_t)(ml * 9 + i) * 9 + j) * K2 + k];
            if (i != j) v += U2[((size_t)(ml * 9 + j) * 9 + i) * K2 + k];
            ws_f[OFF2 + (mg * 45 + pr) * 4 + k] = v;
        } else if (t < 189) {
            const int i = t - 180;
            ws_f[OFF1 + mg * 9 + i] = U1[ml * 9 + i];
        }
    }
}

// ---- P2: per-channel weighting into 32x32x16 B-fragment layout -------------
// Wf[c][s][lane][e] = W_c[k = s*16 + (lane>>5)*8 + e][m = lane&31]  (0-padded)
__global__ __launch_bounds__(256) void symcon_p2(
    const float* __restrict__ ws_f,
    const float* __restrict__ ws1, const float* __restrict__ ws2, const float* __restrict__ ws3,
    const float* __restrict__ wp1, const float* __restrict__ wp2, const float* __restrict__ wp3,
    const float* __restrict__ wd1, const float* __restrict__ wd2, const float* __restrict__ wd3,
    short* __restrict__ Wf)
{
    const int c = blockIdx.x, s = blockIdx.y;
    for (int slot = threadIdx.x; slot < 512; slot += 256) {
        const int lane = slot >> 3, e = slot & 7;
        const int k = s * 16 + ((lane >> 5) << 3) + e;
        const int m = lane & 31;
        float v = 0.f;
        if (k < NM && m < 9) {
            const int pk  = MONO_TBL.v[k];
            const int deg = pk & 15, sub = pk >> 4;
            const float *w1, *w2, *w3; int K2, K3;
            if (m == 0)     { w1 = ws1; w2 = ws2; w3 = ws3; K2 = 2; K3 = 5;  }
            else if (m < 4) { w1 = wp1; w2 = wp2; w3 = wp3; K2 = 3; K3 = 8;  }
            else            { w1 = wd1; w2 = wd2; w3 = wd3; K2 = 4; K3 = 10; }
            if (deg == 1) {
                v = ws_f[OFF1 + m * 9 + sub] * w1[c];
            } else if (deg == 2) {
                const float* u = ws_f + OFF2 + (m * 45 + sub) * 4;
                for (int kk = 0; kk < K2; ++kk) v = fmaf(u[kk], w2[kk * CFEAT + c], v);
            } else {
                const float* u = ws_f + OFF3 + (m * 165 + sub) * 16;
                for (int kk = 0; kk < K3; ++kk) v = fmaf(u[kk], w3[kk * CFEAT + c], v);
            }
        }
        Wf[(((size_t)c * NSTEP + s) * 64 + lane) * 8 + e] = f2bf(v);
    }
}

// ---- hot: register-direct A-fragments, zero Phi-LDS ------------------------
template<int S>
__device__ __forceinline__ void hot_step(const float a0[9], const float a1[9], bool hi,
                                         const short8* __restrict__ Wl,
                                         short8& bcur, f32x16& acc0, f32x16& acc1)
{
    short8 bn;
    if constexpr (S < NSTEP - 1) bn = Wl[(S + 1) * 64];   // prefetch next step's B
    const short8 af0 = build16<S>(a0, hi);
    const short8 af1 = build16<S>(a1, hi);
    acc0 = __builtin_amdgcn_mfma_f32_32x32x16_bf16(af0, bcur, acc0, 0, 0, 0);
    acc1 = __builtin_amdgcn_mfma_f32_32x32x16_bf16(af1, bcur, acc1, 0, 0, 0);
    if constexpr (S < NSTEP - 1) bcur = bn;
}

template<int... S>
__device__ __forceinline__ void run_steps(std::integer_sequence<int, S...>,
                                          const float a0[9], const float a1[9], bool hi,
                                          const short8* __restrict__ Wl,
                                          short8& bcur, f32x16& acc0, f32x16& acc1)
{
    (hot_step<S>(a0, a1, hi, Wl, bcur, acc0, acc1), ...);
}

__global__ __launch_bounds__(256, 4) void symcon_hot(
    const float* __restrict__ A, const short* __restrict__ Wf, float* __restrict__ out)
{
    const int tid = threadIdx.x;
    const int w = tid >> 6, l = tid & 63;
    const int c  = blockIdx.x * 4 + w;     // wave owns one channel
    const int nb = blockIdx.y * 64;        // block owns 64 nodes (2 MFMA row-tiles)
    const bool hi = (l >= 32);
    const int m  = l & 31;

    __shared__ float sA[64 * 37];          // 9472B: A in / out staging, pad 37

    // cooperative A stage: 64 nodes x 36 contiguous floats (4 channels)
    const size_t gbase = (size_t)nb * (CFEAT * 9) + (size_t)(blockIdx.x * 4) * 9;
    for (int e = tid; e < 64 * 36; e += 256) {
        const int n = e / 36, f = e - n * 36;
        sA[n * 37 + f] = A[gbase + (size_t)n * (CFEAT * 9) + f];
    }
    __syncthreads();

    // lane's two nodes (tiles 0/1), own wave's channel column
    float a0[9], a1[9];
    #pragma unroll
    for (int x = 0; x < 9; ++x) {
        a0[x] = sA[m * 37 + w * 9 + x];          // node nb + m
        a1[x] = sA[(32 + m) * 37 + w * 9 + x];   // node nb + 32 + m
    }

    const short8* Wl = (const short8*)Wf + (size_t)c * NSTEP * 64 + l;
    short8 bcur = Wl[0];

    f32x16 acc0 = {0,0,0,0,0,0,0,0,0,0,0,0,0,0,0,0};
    f32x16 acc1 = {0,0,0,0,0,0,0,0,0,0,0,0,0,0,0,0};

    run_steps(std::make_integer_sequence<int, NSTEP>{}, a0, a1, hi, Wl, bcur, acc0, acc1);

    // C/D (m74/m101): col = l&31 = m, row = (reg&3) + 8*(reg>>2) + 4*(l>>5)
    if (m < 9) {
        #pragma unroll
        for (int r = 0; r < 16; ++r) {
            const int row = (r & 3) + 8 * (r >> 2) + (hi ? 4 : 0);
            sA[row * 37 + w * 9 + m] = acc0[r];
        }
        #pragma unroll
        for (int r = 0; r < 16; ++r) {
            const int row = (r & 3) + 8 * (r >> 2) + (hi ? 4 : 0);
            sA[(32 + row) * 37 + w * 9 + m] = acc1[r];
        }
    }
    __syncthreads();

    // cooperative store: dense 144B per node
    for (int e = tid; e < 64 * 36; e += 256) {
        const int n = e / 36, f = e - n * 36;
        out[gbase + (size_t)n * (CFEAT * 9) + f] = sA[n * 37 + f];
    }
}

extern "C" void kernel_launch(void* const* d_in, const int* in_sizes, int n_in,
                              void* d_out, int out_size, void* d_ws, size_t ws_size,
                              hipStream_t stream)
{
    const float* A   = (const float*)d_in[0];
    const float* Us1 = (const float*)d_in[1];  const float* ws1 = (const float*)d_in[2];
    const float* Us2 = (const float*)d_in[3];  const float* ws2 = (const float*)d_in[4];
    const float* Us3 = (const float*)d_in[5];  const float* ws3 = (const float*)d_in[6];
    const float* Up1 = (const float*)d_in[7];  const float* wp1 = (const float*)d_in[8];
    const float* Up2 = (const float*)d_in[9];  const float* wp2 = (const float*)d_in[10];
    const float* Up3 = (const float*)d_in[11]; const float* wp3 = (const float*)d_in[12];
    const float* Ud1 = (const float*)d_in[13]; const float* wd1 = (const float*)d_in[14];
    const float* Ud2 = (const float*)d_in[15]; const float* wd2 = (const float*)d_in[16];
    const float* Ud3 = (const float*)d_in[17]; const float* wd3 = (const float*)d_in[18];
    float* out  = (float*)d_out;
    float* ws_f = (float*)d_ws;
    short* Wf   = (short*)d_ws;

    symcon_p1<<<dim3(9, 12), 256, 0, stream>>>(
        Us1, Us2, Us3, Up1, Up2, Up3, Ud1, Ud2, Ud3, ws_f);

    symcon_p2<<<dim3(CFEAT, NSTEP), 256, 0, stream>>>(
        ws_f, ws1, ws2, ws3, wp1, wp2, wp3, wd1, wd2, wd3, Wf);

    symcon_hot<<<dim3(CFEAT / 4, NODES / 64), 256, 0, stream>>>(A, Wf, out);
}